// Round 9
// baseline (387.304 us; speedup 1.0000x reference)
//
#include <hip/hip_runtime.h>

#define N_NODES 30000
#define N_EDGES 480000
#define ETOT    510000   // edges + self loops
#define F_IN    512
#define WIDTH   256
#define NCLS    40
#define KCAT    768      // WIDTH*3
#define NPAD    48       // NCLS padded to 3 MFMA col-tiles
#define TM      64       // A-tile rows per block (doubled: halves B L2 traffic)
#define BROWS   272      // Bt rows: 256 h-cols + 16 esd-cols (8 used)

typedef __attribute__((ext_vector_type(8))) short short8;
typedef __attribute__((ext_vector_type(4))) float f32x4;

__device__ __forceinline__ unsigned short f2bf(float f){
  unsigned u = __float_as_uint(f);
  u += 0x7fffu + ((u >> 16) & 1u);   // RTNE
  return (unsigned short)(u >> 16);
}
__device__ __forceinline__ float b2f(unsigned short s){
  return __uint_as_float(((unsigned)s) << 16);
}

// async global->LDS, 16B per lane. LDS dest must be linear (base + lane*16).
__device__ __forceinline__ void gload_lds16(const void* g, void* l){
  __builtin_amdgcn_global_load_lds(
      (const __attribute__((address_space(1))) unsigned int*)g,
      (__attribute__((address_space(3))) unsigned int*)l, 16, 0, 0);
}

// ---------------- fused prep: zero + all weight transposes + av folds ----------------
__device__ __forceinline__ void av_body(const float* __restrict__ W,
                                        const float* __restrict__ a_s,
                                        const float* __restrict__ a_d,
                                        unsigned short* __restrict__ Bt, int K, int k){
  int tid = threadIdx.x;           // 256 = 4 heads x 64 ch
  int h = tid >> 6, lane = tid & 63;
  float wv = W[(size_t)k * WIDTH + tid];
  float ps = wv * a_s[tid];
  float pd = wv * a_d[tid];
  #pragma unroll
  for (int off = 32; off; off >>= 1){
    ps += __shfl_down(ps, off, 64);
    pd += __shfl_down(pd, off, 64);
  }
  if (lane == 0){
    Bt[(size_t)(256 + h) * K + k] = f2bf(ps);
    Bt[(size_t)(260 + h) * K + k] = f2bf(pd);
  }
  if (tid < 8) Bt[(size_t)(264 + tid) * K + k] = 0;
}

#define PREP_GRID (118 + 512 + 256 + 256 + 144 + 512 + 256 + 256)   // 2310

__global__ __launch_bounds__(256) void prep_kernel(
    const float* __restrict__ W1, const float* __restrict__ as1, const float* __restrict__ ad1,
    const float* __restrict__ W2, const float* __restrict__ as2, const float* __restrict__ ad2,
    const float* __restrict__ W3, const float* __restrict__ as3, const float* __restrict__ ad3,
    const float* __restrict__ Wo,
    unsigned short* __restrict__ Wt1, unsigned short* __restrict__ Wt2,
    unsigned short* __restrict__ Wt3, unsigned short* __restrict__ WoT,
    int* __restrict__ counts){
  int b = blockIdx.x, tid = threadIdx.x;
  if (b < 118){                          // zero counts
    int i = b * 256 + tid;
    if (i < N_NODES) counts[i] = 0;
    return;
  }
  b -= 118;
  if (b < 512){                          // Wt1: W1[512][256] -> [256][512] bf16
    int n = b >> 1, k = (b & 1) * 256 + tid;
    Wt1[(size_t)n * F_IN + k] = f2bf(W1[(size_t)k * WIDTH + n]);
    return;
  }
  b -= 512;
  if (b < 256){ Wt2[(size_t)b * WIDTH + tid] = f2bf(W2[(size_t)tid * WIDTH + b]); return; }
  b -= 256;
  if (b < 256){ Wt3[(size_t)b * WIDTH + tid] = f2bf(W3[(size_t)tid * WIDTH + b]); return; }
  b -= 256;
  if (b < 144){                          // WoT pad+transpose: 48*768
    int i = b * 256 + tid;
    int c = i / KCAT, k = i - c * KCAT;
    WoT[i] = (c < NCLS) ? f2bf(Wo[(size_t)k * NCLS + c]) : (unsigned short)0;
    return;
  }
  b -= 144;
  if (b < 512){ av_body(W1, as1, ad1, Wt1, F_IN, b); return; }
  b -= 512;
  if (b < 256){ av_body(W2, as2, ad2, Wt2, WIDTH, b); return; }
  b -= 256;
  av_body(W3, as3, ad3, Wt3, WIDTH, b);
}

// ---------------- CSR build ----------------
__global__ void hist_kernel(const int* __restrict__ ei, int* __restrict__ counts){
  int e = blockIdx.x * blockDim.x + threadIdx.x;
  if (e < ETOT){
    int d = (e < N_EDGES) ? ei[N_EDGES + e] : (e - N_EDGES);
    atomicAdd(&counts[d], 1);
  }
}

__global__ __launch_bounds__(1024) void scan_part_kernel(const int* __restrict__ counts,
                                                         int* __restrict__ offsets,
                                                         int* __restrict__ bsum, int n){
  __shared__ int wsum[16];
  int tid = threadIdx.x, lane = tid & 63, wid = tid >> 6;
  int i = blockIdx.x * 1024 + tid;
  int v = (i < n) ? counts[i] : 0;
  int x = v;
  #pragma unroll
  for (int off = 1; off < 64; off <<= 1){
    int t = __shfl_up(x, off, 64);
    if (lane >= off) x += t;
  }
  if (lane == 63) wsum[wid] = x;
  __syncthreads();
  if (wid == 0){
    int s = (lane < 16) ? wsum[lane] : 0;
    #pragma unroll
    for (int off = 1; off < 16; off <<= 1){
      int t = __shfl_up(s, off, 64);
      if (lane >= off) s += t;
    }
    if (lane < 16) wsum[lane] = s;
  }
  __syncthreads();
  int wp = (wid > 0) ? wsum[wid - 1] : 0;
  if (i < n) offsets[i] = x - v + wp;       // exclusive within block
  if (tid == 0) bsum[blockIdx.x] = wsum[15];
}

__global__ __launch_bounds__(64) void scan_bsum_kernel(int* __restrict__ bsum,
                                                       int* __restrict__ offsets,
                                                       int nb, int n){
  int lane = threadIdx.x;
  int v = (lane < nb) ? bsum[lane] : 0;
  int x = v;
  #pragma unroll
  for (int off = 1; off < 64; off <<= 1){
    int t = __shfl_up(x, off, 64);
    if (lane >= off) x += t;
  }
  if (lane < nb) bsum[lane] = x - v;        // exclusive block prefix
  if (lane == nb - 1) offsets[n] = x;       // grand total
}

__global__ __launch_bounds__(1024) void scan_add_kernel(int* __restrict__ offsets,
                                                        int* __restrict__ cursor,
                                                        const int* __restrict__ bsum, int n){
  int i = blockIdx.x * 1024 + threadIdx.x;
  if (i < n){
    int o = offsets[i] + bsum[blockIdx.x];
    offsets[i] = o;
    cursor[i] = o;
  }
}

// ---------------- B-reuse fused GEMM, one 64-row tile per block ----------------
// TM=64 halves B L2 traffic vs TM=32 (8 waves read disjoint 32-col B slices, so
// each block reads the whole B panel once: 469 x 278KB = 130MB vs 260MB -- rounds
// 0-6 showed all gemm variants pinned at ~7 TB/s aggregate L2/L3 traffic, i.e.
// B-traffic-bound, not schedule-bound). A is staged per 256-wide K-pass into a
// 32KB buffer; hstage UNIONS onto the same buffer after the k-loop -> LDS
// 51.2KB -> 3 blocks/CU. es/ed are 8 extra B cols (W@a precomputed), K-split
// across waves, MFMA'd in whichever pass owns their k-range, combined via cmbE.
// Layer-1 dispatch also carries the edge SCATTER as extra blocks (independent
// work; hides scatter latency + one dispatch drain).
template<int K, bool AF32>
__global__ __launch_bounds__(512, 4)
void gemm_bres_kernel(const void* __restrict__ Araw,
                      const unsigned short* __restrict__ Bt,
                      float* __restrict__ es,
                      float* __restrict__ ed,
                      unsigned short* __restrict__ hb,
                      int M, int ngb,
                      const int* __restrict__ ei,
                      int* __restrict__ cursor,
                      int* __restrict__ srcs){
  constexpr int KT = K / 32;       // k-steps total (8 or 16)
  constexpr int NP = K / 256;      // K-passes (1 or 2)
  constexpr int KE = KT / 8;       // esd k-steps per wave (1 or 2)
  __shared__ unsigned short Abuf[TM * 256];   // 32KB: A pass-tile, then hstage
  __shared__ float cmbE[8][TM][9];            // 18KB

  int tid = threadIdx.x;

  // ---- fused scatter section (layer-1 dispatch only) ----
  if ((int)blockIdx.x >= ngb){
    int e = ((int)blockIdx.x - ngb) * 512 + tid;
    if (e < ETOT){
      int s, d;
      if (e < N_EDGES){ s = ei[e]; d = ei[N_EDGES + e]; }
      else { s = e - N_EDGES; d = s; }
      int pos = atomicAdd(&cursor[d], 1);
      srcs[pos] = s;
    }
    return;
  }

  int lane = tid & 63, w = tid >> 6;
  int l15 = lane & 15, quad = lane >> 4;
  int c0 = w * 32;
  int r0 = blockIdx.x * TM;

  // ---- small resident esd-column fragments ----
  short8 Bfe[KE];
  #pragma unroll
  for (int i = 0; i < KE; ++i){
    int kt = w * KE + i;
    Bfe[i] = *(const short8*)(Bt + (size_t)(256 + l15) * K + kt*32 + quad*8);
  }

  f32x4 acc[4][2];
  f32x4 eacc[4];
  #pragma unroll
  for (int s = 0; s < 4; ++s){
    acc[s][0] = (f32x4){0.f,0.f,0.f,0.f};
    acc[s][1] = (f32x4){0.f,0.f,0.f,0.f};
    eacc[s]   = (f32x4){0.f,0.f,0.f,0.f};
  }

  // ---- K-pass loop: stage A pass-tile, then ds_read + MFMA ----
  #pragma unroll 1
  for (int p = 0; p < NP; ++p){
    if (p) __syncthreads();               // all reads of prior pass done
    if constexpr (AF32){
      // f32 source: 64 rows x 256 k x 4B per pass; reg-stage + cvt (va dies
      // before MFMA -> peak VGPR stays under the 128 cap)
      const char* xb = (const char*)Araw;
      uint4 va[8];
      #pragma unroll
      for (int i = 0; i < 8; ++i){
        int L32 = (i * 512 + tid) * 16;   // 0..65535
        int row = L32 >> 10;              // 1024B per row-pass
        int colb = L32 & 1023;
        int grow = r0 + row; if (grow > M - 1) grow = M - 1;
        va[i] = *(const uint4*)(xb + (size_t)grow * (K*4) + p*1024 + colb);
      }
      #pragma unroll
      for (int i = 0; i < 8; ++i){
        int ob = (i * 512 + tid) * 8;     // 0..32767
        int row = ob >> 9;                // 512B per LDS row
        unsigned u0 = (unsigned)f2bf(__uint_as_float(va[i].x)) |
                      ((unsigned)f2bf(__uint_as_float(va[i].y)) << 16);
        unsigned u1 = (unsigned)f2bf(__uint_as_float(va[i].z)) |
                      ((unsigned)f2bf(__uint_as_float(va[i].w)) << 16);
        uint2 uv; uv.x = u0; uv.y = u1;
        *(uint2*)((char*)Abuf + (ob ^ ((row & 7) << 4))) = uv;
      }
    } else {
      const char* Ab = (const char*)Araw;
      #pragma unroll
      for (int c = 0; c < 4; ++c){
        int L = (c * 512 + tid) * 16;     // 0..32767 linear LDS byte offset
        int row = L >> 9;                 // 512B per LDS row
        int colb = L & 511;
        int grow = r0 + row; if (grow > M - 1) grow = M - 1;
        gload_lds16(Ab + (size_t)grow * (K*2) + p*512 + (colb ^ ((row & 7) << 4)),
                    (char*)Abuf + L);
      }
    }
    __syncthreads();                      // A pass-tile ready (drains DMA)

    // B fragments for this pass (16 loads; disjoint cols per wave)
    short8 Bf[8][2];
    #pragma unroll
    for (int kt2 = 0; kt2 < 8; ++kt2){
      #pragma unroll
      for (int ct = 0; ct < 2; ++ct){
        Bf[kt2][ct] = *(const short8*)(Bt + (size_t)(c0 + ct*16 + l15) * K
                                          + (p*8 + kt2)*32 + quad*8);
      }
    }
    __builtin_amdgcn_sched_barrier(0);

    #pragma unroll
    for (int s = 0; s < 4; ++s){
      int row = s * 16 + l15;
      int swzus = (row & 7) << 3;         // ushort-index XOR = byte XOR >> 1
      const unsigned short* base = Abuf + row * 256;
      #pragma unroll
      for (int kt2 = 0; kt2 < 8; ++kt2){
        short8 af = *(const short8*)(base + ((kt2*32 + quad*8) ^ swzus));
        acc[s][0] = __builtin_amdgcn_mfma_f32_16x16x32_bf16(af, Bf[kt2][0], acc[s][0], 0, 0, 0);
        acc[s][1] = __builtin_amdgcn_mfma_f32_16x16x32_bf16(af, Bf[kt2][1], acc[s][1], 0, 0, 0);
      }
    }
    // esd columns whose k-range lives in this pass
    #pragma unroll
    for (int i = 0; i < KE; ++i){
      int kt = w * KE + i;
      if (kt >= p*8 && kt < p*8 + 8){
        int kt2 = kt - p*8;
        #pragma unroll
        for (int s = 0; s < 4; ++s){
          int row = s * 16 + l15;
          int swzus = (row & 7) << 3;
          const unsigned short* base = Abuf + row * 256;
          short8 af = *(const short8*)(base + ((kt2*32 + quad*8) ^ swzus));
          eacc[s] = __builtin_amdgcn_mfma_f32_16x16x32_bf16(af, Bfe[i], eacc[s], 0, 0, 0);
        }
      }
    }
  }

  // ---- epilogue: hstage UNIONS onto Abuf ----
  __syncthreads();                        // all Abuf reads complete
  #pragma unroll
  for (int s = 0; s < 4; ++s){
    #pragma unroll
    for (int r = 0; r < 4; ++r){
      int row = s * 16 + quad * 4 + r;
      int swz = (row & 7) << 4;
      #pragma unroll
      for (int ct = 0; ct < 2; ++ct){
        int colb = (c0 + ct * 16 + l15) * 2;
        *(unsigned short*)((char*)Abuf + ((row * 512 + colb) ^ swz))
            = f2bf(acc[s][ct][r]);
      }
      if (l15 < 8) cmbE[w][row][l15] = eacc[s][r];
    }
  }
  __syncthreads();

  // coalesced h stores: full 512B rows
  #pragma unroll
  for (int c = 0; c < 4; ++c){
    int us = (c * 512 + tid) * 8;         // ushort index in 64x256 tile
    int row = us >> 8, col = us & 255;
    int grow = r0 + row;
    if (grow < M){
      uint4 v = *(const uint4*)((const char*)Abuf + ((row * 512 + col * 2) ^ ((row & 7) << 4)));
      *(uint4*)(hb + (size_t)grow * WIDTH + col) = v;
    }
  }
  // es/ed combine + store (separate 16B-row arrays)
  {
    int row = tid >> 3, j = tid & 7;
    int grow = r0 + row;
    if (grow < M){
      float v = 0.f;
      #pragma unroll
      for (int ww = 0; ww < 8; ++ww) v += cmbE[ww][row][j];
      if (j < 4) es[(size_t)grow * 4 + j] = v;
      else       ed[(size_t)grow * 4 + (j - 4)] = v;
    }
  }
}

// ---------------- aggregation: one node per HALF-wave ----------------
__global__ __launch_bounds__(256) void agg_kernel(const int* __restrict__ offsets,
                                                  const int* __restrict__ srcs,
                                                  const float* __restrict__ es,
                                                  const float* __restrict__ ed,
                                                  const unsigned short* __restrict__ hb,
                                                  const float* __restrict__ bias,
                                                  unsigned short* __restrict__ hout){
  __shared__ float eLds[8][64][4];
  __shared__ int   sLds[8][64];
  int wid = threadIdx.x >> 6;
  int lane = threadIdx.x & 63;
  int half = lane >> 5, l32 = lane & 31;
  int slot = wid * 2 + half;
  int n = blockIdx.x * 8 + slot;
  int base = offsets[n];
  int deg = offsets[n + 1] - base;
  float4 edv = *(const float4*)(ed + (size_t)n * 4);

  // pass 1: strided over 32 lanes; cache first 64 edges in LDS; per-head max
  float m0 = -1e30f, m1 = -1e30f, m2 = -1e30f, m3 = -1e30f;
  for (int i = l32; i < deg; i += 32){
    int s = srcs[base + i];
    float4 ev = *(const float4*)(es + (size_t)s * 4);
    float e0 = ev.x + edv.x, e1 = ev.y + edv.y, e2 = ev.z + edv.z, e3 = ev.w + edv.w;
    e0 = e0 > 0.f ? e0 : 0.2f * e0;
    e1 = e1 > 0.f ? e1 : 0.2f * e1;
    e2 = e2 > 0.f ? e2 : 0.2f * e2;
    e3 = e3 > 0.f ? e3 : 0.2f * e3;
    if (i < 64){
      sLds[slot][i] = s;
      *(float4*)(&eLds[slot][i][0]) = (float4){e0, e1, e2, e3};
    }
    m0 = fmaxf(m0, e0); m1 = fmaxf(m1, e1); m2 = fmaxf(m2, e2); m3 = fmaxf(m3, e3);
  }
  #pragma unroll
  for (int off = 1; off < 32; off <<= 1){
    m0 = fmaxf(m0, __shfl_xor(m0, off, 64));
    m1 = fmaxf(m1, __shfl_xor(m1, off, 64));
    m2 = fmaxf(m2, __shfl_xor(m2, off, 64));
    m3 = fmaxf(m3, __shfl_xor(m3, off, 64));
  }
  int head = l32 >> 3;                       // 8 lanes per head, 8 ch/lane
  float mh  = (head == 0) ? m0 : (head == 1) ? m1 : (head == 2) ? m2 : m3;
  float edh = (head == 0) ? edv.x : (head == 1) ? edv.y : (head == 2) ? edv.z : edv.w;

  // pass 2: 8 edges per iteration, 8 gathers in flight
  float2 a0 = {0.f,0.f}, a1 = {0.f,0.f}, a2 = {0.f,0.f}, a3 = {0.f,0.f};
  float den = 0.f;
  const unsigned short* hcol = hb + 8 * l32;
  for (int i = 0; i < deg; i += 8){
    int sidx[8]; float wgt[8];
    #pragma unroll
    for (int u = 0; u < 8; ++u){
      int idx = i + u;
      bool v = idx < deg;
      float le; int s;
      if (idx < 64 || !v){
        int ic = v ? idx : 0;
        if (ic >= 64) ic = 0;
        s  = sLds[slot][ic];
        le = eLds[slot][ic][head];
      } else {
        s = srcs[base + idx];
        float e = es[(size_t)s * 4 + head] + edh;
        le = e > 0.f ? e : 0.2f * e;
      }
      sidx[u] = s;
      wgt[u] = v ? __expf(le - mh) : 0.f;
    }
    uint4 hv[8];
    #pragma unroll
    for (int u = 0; u < 8; ++u)
      hv[u] = *(const uint4*)(hcol + (size_t)sidx[u] * WIDTH);
    #pragma unroll
    for (int u = 0; u < 8; ++u){
      float wu = wgt[u];
      den += wu;
      a0.x += wu * __uint_as_float(hv[u].x << 16);
      a0.y += wu * __uint_as_float(hv[u].x & 0xffff0000u);
      a1.x += wu * __uint_as_float(hv[u].y << 16);
      a1.y += wu * __uint_as_float(hv[u].y & 0xffff0000u);
      a2.x += wu * __uint_as_float(hv[u].z << 16);
      a2.y += wu * __uint_as_float(hv[u].z & 0xffff0000u);
      a3.x += wu * __uint_as_float(hv[u].w << 16);
      a3.y += wu * __uint_as_float(hv[u].w & 0xffff0000u);
    }
  }
  float inv = 1.0f / den;
  const float* bp = bias + 8 * l32;
  float4 bv0 = *(const float4*)(bp);
  float4 bv1 = *(const float4*)(bp + 4);
  float o0 = fmaxf(a0.x * inv + bv0.x, 0.f);
  float o1 = fmaxf(a0.y * inv + bv0.y, 0.f);
  float o2 = fmaxf(a1.x * inv + bv0.z, 0.f);
  float o3 = fmaxf(a1.y * inv + bv0.w, 0.f);
  float o4 = fmaxf(a2.x * inv + bv1.x, 0.f);
  float o5 = fmaxf(a2.y * inv + bv1.y, 0.f);
  float o6 = fmaxf(a3.x * inv + bv1.z, 0.f);
  float o7 = fmaxf(a3.y * inv + bv1.w, 0.f);
  uint4 o;
  o.x = (unsigned)f2bf(o0) | ((unsigned)f2bf(o1) << 16);
  o.y = (unsigned)f2bf(o2) | ((unsigned)f2bf(o3) << 16);
  o.z = (unsigned)f2bf(o4) | ((unsigned)f2bf(o5) << 16);
  o.w = (unsigned)f2bf(o6) | ((unsigned)f2bf(o7) << 16);
  *(uint4*)(hout + (size_t)n * WIDTH + 8 * l32) = o;
}

// ---------------- output head as MFMA GEMM ----------------
__global__ __launch_bounds__(256) void out_gemm_kernel(const unsigned short* __restrict__ h1,
                                                       const unsigned short* __restrict__ h2,
                                                       const unsigned short* __restrict__ h3,
                                                       const unsigned short* __restrict__ WoT,
                                                       const float* __restrict__ bo,
                                                       float* __restrict__ out){
  int tid = threadIdx.x, lane = tid & 63, wid = tid >> 6;
  int l15 = lane & 15, quad = lane >> 4;
  int m0 = blockIdx.x * 64 + 16 * wid;

  f32x4 acc[3];
  #pragma unroll
  for (int t = 0; t < 3; ++t) acc[t] = (f32x4){0.f, 0.f, 0.f, 0.f};

  int arow = m0 + l15; if (arow >= N_NODES) arow = N_NODES - 1;

  #pragma unroll
  for (int part = 0; part < 3; ++part){
    const unsigned short* hp = (part == 0) ? h1 : (part == 1) ? h2 : h3;
    const unsigned short* ap = hp + (size_t)arow * WIDTH;
    #pragma unroll
    for (int k0 = 0; k0 < WIDTH; k0 += 32){
      short8 af = *(const short8*)(ap + k0 + quad * 8);
      int kk = part * WIDTH + k0;
      #pragma unroll
      for (int t = 0; t < 3; ++t){
        short8 bf = *(const short8*)(WoT + (size_t)(16 * t + l15) * KCAT + kk + quad * 8);
        acc[t] = __builtin_amdgcn_mfma_f32_16x16x32_bf16(af, bf, acc[t], 0, 0, 0);
      }
    }
  }

  int r0 = m0 + quad * 4;
  #pragma unroll
  for (int t = 0; t < 3; ++t){
    int col = 16 * t + l15;
    if (col < NCLS){
      float bc = bo[col];
      #pragma unroll
      for (int r = 0; r < 4; ++r){
        int grow = r0 + r;
        if (grow < N_NODES) out[(size_t)grow * NCLS + col] = acc[t][r] + bc;
      }
    }
  }
}

// ---------------- host launch ----------------
static inline size_t align256(size_t x){ return (x + 255) & ~(size_t)255; }

extern "C" void kernel_launch(void* const* d_in, const int* in_sizes, int n_in,
                              void* d_out, int out_size, void* d_ws, size_t ws_size,
                              hipStream_t stream) {
  const float* x   = (const float*)d_in[0];
  const int*   ei  = (const int*)  d_in[1];
  const float* W1  = (const float*)d_in[2];
  const float* as1 = (const float*)d_in[3];
  const float* ad1 = (const float*)d_in[4];
  const float* b1  = (const float*)d_in[5];
  const float* W2  = (const float*)d_in[6];
  const float* as2 = (const float*)d_in[7];
  const float* ad2 = (const float*)d_in[8];
  const float* b2  = (const float*)d_in[9];
  const float* W3  = (const float*)d_in[10];
  const float* as3 = (const float*)d_in[11];
  const float* ad3 = (const float*)d_in[12];
  const float* b3  = (const float*)d_in[13];
  const float* Wo  = (const float*)d_in[14];
  const float* bo  = (const float*)d_in[15];
  float* out = (float*)d_out;

  char* p = (char*)d_ws;
  auto take = [&](size_t bytes) -> char* { char* cur = p; p += align256(bytes); return cur; };

  unsigned short* Wt1   = (unsigned short*)take((size_t)BROWS * F_IN * 2);
  unsigned short* Wt2   = (unsigned short*)take((size_t)BROWS * WIDTH * 2);
  unsigned short* Wt3   = (unsigned short*)take((size_t)BROWS * WIDTH * 2);
  unsigned short* WoT   = (unsigned short*)take((size_t)NPAD * KCAT * 2);
  unsigned short* hs    = (unsigned short*)take((size_t)N_NODES * WIDTH * 2);
  float*          es    = (float*)take((size_t)N_NODES * 4 * 4);
  float*          ed    = (float*)take((size_t)N_NODES * 4 * 4);
  unsigned short* h1b   = (unsigned short*)take((size_t)N_NODES * WIDTH * 2);
  unsigned short* h2b   = (unsigned short*)take((size_t)N_NODES * WIDTH * 2);
  unsigned short* h3b   = (unsigned short*)take((size_t)N_NODES * WIDTH * 2);
  int*            counts  = (int*)take((size_t)N_NODES * 4);
  int*            offsets = (int*)take((size_t)(N_NODES + 1) * 4);
  int*            cursor  = (int*)take((size_t)N_NODES * 4);
  int*            srcs    = (int*)take((size_t)ETOT * 4);
  int*            bsum    = (int*)take((size_t)64 * 4);

  // fused prep: zero + transposes + av folds (1 dispatch)
  prep_kernel<<<PREP_GRID, 256, 0, stream>>>(W1, as1, ad1, W2, as2, ad2,
                                             W3, as3, ad3, Wo,
                                             Wt1, Wt2, Wt3, WoT, counts);

  // CSR build: hist + 3-dispatch parallel scan (scatter fused into gemm1)
  const int nb = (N_NODES + 1023) / 1024;          // 30
  hist_kernel<<<(ETOT + 255) / 256, 256, 0, stream>>>(ei, counts);
  scan_part_kernel<<<nb, 1024, 0, stream>>>(counts, offsets, bsum, N_NODES);
  scan_bsum_kernel<<<1, 64, 0, stream>>>(bsum, offsets, nb, N_NODES);
  scan_add_kernel<<<nb, 1024, 0, stream>>>(offsets, cursor, bsum, N_NODES);

  const int ntiles = (N_NODES + TM - 1) / TM;      // 469
  const int nscat  = (ETOT + 511) / 512;           // 997
  const int agg_grid = N_NODES / 8;                // 3750
  const int out_grid = (N_NODES + 63) / 64;        // 469

  // layer 1 (A = x, f32) + fused scatter blocks
  gemm_bres_kernel<F_IN, true><<<ntiles + nscat, 512, 0, stream>>>(
      x, Wt1, es, ed, hs, N_NODES, ntiles, ei, cursor, srcs);
  agg_kernel<<<agg_grid, 256, 0, stream>>>(offsets, srcs, es, ed, hs, b1, h1b);
  // layer 2
  gemm_bres_kernel<WIDTH, false><<<ntiles, 512, 0, stream>>>(
      h1b, Wt2, es, ed, hs, N_NODES, ntiles, ei, cursor, srcs);
  agg_kernel<<<agg_grid, 256, 0, stream>>>(offsets, srcs, es, ed, hs, b2, h2b);
  // layer 3
  gemm_bres_kernel<WIDTH, false><<<ntiles, 512, 0, stream>>>(
      h2b, Wt3, es, ed, hs, N_NODES, ntiles, ei, cursor, srcs);
  agg_kernel<<<agg_grid, 256, 0, stream>>>(offsets, srcs, es, ed, hs, b3, h3b);

  // output head (MFMA GEMM)
  out_gemm_kernel<<<out_grid, 256, 0, stream>>>(h1b, h2b, h3b, WoT, bo, out);
}

// Round 10
// 367.583 us; speedup vs baseline: 1.0537x; 1.0537x over previous
//
#include <hip/hip_runtime.h>

#define N_NODES 30000
#define N_EDGES 480000
#define ETOT    510000   // edges + self loops
#define F_IN    512
#define WIDTH   256
#define NCLS    40
#define KCAT    768      // WIDTH*3
#define NPAD    48       // NCLS padded to 3 MFMA col-tiles
#define TM      64       // A-tile rows per block (halves B L2 traffic)
#define BROWS   272      // Bt rows: 256 h-cols + 16 esd-cols (8 used)

typedef __attribute__((ext_vector_type(8))) short short8;
typedef __attribute__((ext_vector_type(4))) float f32x4;

__device__ __forceinline__ unsigned short f2bf(float f){
  unsigned u = __float_as_uint(f);
  u += 0x7fffu + ((u >> 16) & 1u);   // RTNE
  return (unsigned short)(u >> 16);
}
__device__ __forceinline__ float b2f(unsigned short s){
  return __uint_as_float(((unsigned)s) << 16);
}

// async global->LDS, 16B per lane. LDS dest must be linear (base + lane*16).
__device__ __forceinline__ void gload_lds16(const void* g, void* l){
  __builtin_amdgcn_global_load_lds(
      (const __attribute__((address_space(1))) unsigned int*)g,
      (__attribute__((address_space(3))) unsigned int*)l, 16, 0, 0);
}

// ---------------- fused prep: zero + all weight transposes + av folds ----------------
__device__ __forceinline__ void av_body(const float* __restrict__ W,
                                        const float* __restrict__ a_s,
                                        const float* __restrict__ a_d,
                                        unsigned short* __restrict__ Bt, int K, int k){
  int tid = threadIdx.x;           // 256 = 4 heads x 64 ch
  int h = tid >> 6, lane = tid & 63;
  float wv = W[(size_t)k * WIDTH + tid];
  float ps = wv * a_s[tid];
  float pd = wv * a_d[tid];
  #pragma unroll
  for (int off = 32; off; off >>= 1){
    ps += __shfl_down(ps, off, 64);
    pd += __shfl_down(pd, off, 64);
  }
  if (lane == 0){
    Bt[(size_t)(256 + h) * K + k] = f2bf(ps);
    Bt[(size_t)(260 + h) * K + k] = f2bf(pd);
  }
  if (tid < 8) Bt[(size_t)(264 + tid) * K + k] = 0;
}

#define PREP_GRID (118 + 512 + 256 + 256 + 144 + 512 + 256 + 256)   // 2310

__global__ __launch_bounds__(256) void prep_kernel(
    const float* __restrict__ W1, const float* __restrict__ as1, const float* __restrict__ ad1,
    const float* __restrict__ W2, const float* __restrict__ as2, const float* __restrict__ ad2,
    const float* __restrict__ W3, const float* __restrict__ as3, const float* __restrict__ ad3,
    const float* __restrict__ Wo,
    unsigned short* __restrict__ Wt1, unsigned short* __restrict__ Wt2,
    unsigned short* __restrict__ Wt3, unsigned short* __restrict__ WoT,
    int* __restrict__ counts){
  int b = blockIdx.x, tid = threadIdx.x;
  if (b < 118){                          // zero counts
    int i = b * 256 + tid;
    if (i < N_NODES) counts[i] = 0;
    return;
  }
  b -= 118;
  if (b < 512){                          // Wt1: W1[512][256] -> [256][512] bf16
    int n = b >> 1, k = (b & 1) * 256 + tid;
    Wt1[(size_t)n * F_IN + k] = f2bf(W1[(size_t)k * WIDTH + n]);
    return;
  }
  b -= 512;
  if (b < 256){ Wt2[(size_t)b * WIDTH + tid] = f2bf(W2[(size_t)tid * WIDTH + b]); return; }
  b -= 256;
  if (b < 256){ Wt3[(size_t)b * WIDTH + tid] = f2bf(W3[(size_t)tid * WIDTH + b]); return; }
  b -= 256;
  if (b < 144){                          // WoT pad+transpose: 48*768
    int i = b * 256 + tid;
    int c = i / KCAT, k = i - c * KCAT;
    WoT[i] = (c < NCLS) ? f2bf(Wo[(size_t)k * NCLS + c]) : (unsigned short)0;
    return;
  }
  b -= 144;
  if (b < 512){ av_body(W1, as1, ad1, Wt1, F_IN, b); return; }
  b -= 512;
  if (b < 256){ av_body(W2, as2, ad2, Wt2, WIDTH, b); return; }
  b -= 256;
  av_body(W3, as3, ad3, Wt3, WIDTH, b);
}

// ---------------- CSR build ----------------
__global__ void hist_kernel(const int* __restrict__ ei, int* __restrict__ counts){
  int e = blockIdx.x * blockDim.x + threadIdx.x;
  if (e < ETOT){
    int d = (e < N_EDGES) ? ei[N_EDGES + e] : (e - N_EDGES);
    atomicAdd(&counts[d], 1);
  }
}

__global__ __launch_bounds__(1024) void scan_part_kernel(const int* __restrict__ counts,
                                                         int* __restrict__ offsets,
                                                         int* __restrict__ bsum, int n){
  __shared__ int wsum[16];
  int tid = threadIdx.x, lane = tid & 63, wid = tid >> 6;
  int i = blockIdx.x * 1024 + tid;
  int v = (i < n) ? counts[i] : 0;
  int x = v;
  #pragma unroll
  for (int off = 1; off < 64; off <<= 1){
    int t = __shfl_up(x, off, 64);
    if (lane >= off) x += t;
  }
  if (lane == 63) wsum[wid] = x;
  __syncthreads();
  if (wid == 0){
    int s = (lane < 16) ? wsum[lane] : 0;
    #pragma unroll
    for (int off = 1; off < 16; off <<= 1){
      int t = __shfl_up(s, off, 64);
      if (lane >= off) s += t;
    }
    if (lane < 16) wsum[lane] = s;
  }
  __syncthreads();
  int wp = (wid > 0) ? wsum[wid - 1] : 0;
  if (i < n) offsets[i] = x - v + wp;       // exclusive within block
  if (tid == 0) bsum[blockIdx.x] = wsum[15];
}

__global__ __launch_bounds__(64) void scan_bsum_kernel(int* __restrict__ bsum,
                                                       int* __restrict__ offsets,
                                                       int nb, int n){
  int lane = threadIdx.x;
  int v = (lane < nb) ? bsum[lane] : 0;
  int x = v;
  #pragma unroll
  for (int off = 1; off < 64; off <<= 1){
    int t = __shfl_up(x, off, 64);
    if (lane >= off) x += t;
  }
  if (lane < nb) bsum[lane] = x - v;        // exclusive block prefix
  if (lane == nb - 1) offsets[n] = x;       // grand total
}

__global__ __launch_bounds__(1024) void scan_add_kernel(int* __restrict__ offsets,
                                                        int* __restrict__ cursor,
                                                        const int* __restrict__ bsum, int n){
  int i = blockIdx.x * 1024 + threadIdx.x;
  if (i < n){
    int o = offsets[i] + bsum[blockIdx.x];
    offsets[i] = o;
    cursor[i] = o;
  }
}

// ---------------- B-reuse fused GEMM, one 64-row tile per block ----------------
// TM=64 halves B L2 traffic vs TM=32. Round-9 PMC showed the K=512 instantiation
// SPILLING (WRITE_SIZE 100MB vs 16MB expected, ~350B/thread scratch): MFMA-phase
// pressure acc(32)+eacc(16)+Bf[8][2](64)+Bfe(8)+addr ~= 135 > 128 cap. Fix: B
// bursts of 4 k-steps (Bf[4][2]=32 VGPR, #pragma unroll 1 so lifetimes don't
// overlap) -> peak ~103 < 128. A staged per 256-wide K-pass into 32KB buffer;
// hstage UNIONS onto it after the k-loop -> LDS 51.2KB. es/ed are 8 extra B
// cols (W@a precomputed), K-split across waves, combined via cmbE. Layer-1
// dispatch carries the edge SCATTER as extra blocks.
template<int K, bool AF32>
__global__ __launch_bounds__(512, 4)
void gemm_bres_kernel(const void* __restrict__ Araw,
                      const unsigned short* __restrict__ Bt,
                      float* __restrict__ es,
                      float* __restrict__ ed,
                      unsigned short* __restrict__ hb,
                      int M, int ngb,
                      const int* __restrict__ ei,
                      int* __restrict__ cursor,
                      int* __restrict__ srcs){
  constexpr int KT = K / 32;       // k-steps total (8 or 16)
  constexpr int NP = K / 256;      // K-passes (1 or 2)
  constexpr int KE = KT / 8;       // esd k-steps per wave (1 or 2)
  __shared__ unsigned short Abuf[TM * 256];   // 32KB: A pass-tile, then hstage
  __shared__ float cmbE[8][TM][9];            // 18KB

  int tid = threadIdx.x;

  // ---- fused scatter section (layer-1 dispatch only) ----
  if ((int)blockIdx.x >= ngb){
    int e = ((int)blockIdx.x - ngb) * 512 + tid;
    if (e < ETOT){
      int s, d;
      if (e < N_EDGES){ s = ei[e]; d = ei[N_EDGES + e]; }
      else { s = e - N_EDGES; d = s; }
      int pos = atomicAdd(&cursor[d], 1);
      srcs[pos] = s;
    }
    return;
  }

  int lane = tid & 63, w = tid >> 6;
  int l15 = lane & 15, quad = lane >> 4;
  int c0 = w * 32;
  int r0 = blockIdx.x * TM;

  // ---- small resident esd-column fragments ----
  short8 Bfe[KE];
  #pragma unroll
  for (int i = 0; i < KE; ++i){
    int kt = w * KE + i;
    Bfe[i] = *(const short8*)(Bt + (size_t)(256 + l15) * K + kt*32 + quad*8);
  }

  f32x4 acc[4][2];
  f32x4 eacc[4];
  #pragma unroll
  for (int s = 0; s < 4; ++s){
    acc[s][0] = (f32x4){0.f,0.f,0.f,0.f};
    acc[s][1] = (f32x4){0.f,0.f,0.f,0.f};
    eacc[s]   = (f32x4){0.f,0.f,0.f,0.f};
  }

  // ---- K-pass loop: stage A pass-tile, then ds_read + MFMA ----
  #pragma unroll 1
  for (int p = 0; p < NP; ++p){
    if (p) __syncthreads();               // all reads of prior pass done
    if constexpr (AF32){
      // f32 source: 64 rows x 256 k x 4B per pass; reg-stage + cvt (va dies
      // before MFMA)
      const char* xb = (const char*)Araw;
      uint4 va[8];
      #pragma unroll
      for (int i = 0; i < 8; ++i){
        int L32 = (i * 512 + tid) * 16;   // 0..65535
        int row = L32 >> 10;              // 1024B per row-pass
        int colb = L32 & 1023;
        int grow = r0 + row; if (grow > M - 1) grow = M - 1;
        va[i] = *(const uint4*)(xb + (size_t)grow * (K*4) + p*1024 + colb);
      }
      #pragma unroll
      for (int i = 0; i < 8; ++i){
        int ob = (i * 512 + tid) * 8;     // 0..32767
        int row = ob >> 9;                // 512B per LDS row
        unsigned u0 = (unsigned)f2bf(__uint_as_float(va[i].x)) |
                      ((unsigned)f2bf(__uint_as_float(va[i].y)) << 16);
        unsigned u1 = (unsigned)f2bf(__uint_as_float(va[i].z)) |
                      ((unsigned)f2bf(__uint_as_float(va[i].w)) << 16);
        uint2 uv; uv.x = u0; uv.y = u1;
        *(uint2*)((char*)Abuf + (ob ^ ((row & 7) << 4))) = uv;
      }
    } else {
      const char* Ab = (const char*)Araw;
      #pragma unroll
      for (int c = 0; c < 4; ++c){
        int L = (c * 512 + tid) * 16;     // 0..32767 linear LDS byte offset
        int row = L >> 9;                 // 512B per LDS row
        int colb = L & 511;
        int grow = r0 + row; if (grow > M - 1) grow = M - 1;
        gload_lds16(Ab + (size_t)grow * (K*2) + p*512 + (colb ^ ((row & 7) << 4)),
                    (char*)Abuf + L);
      }
    }
    __syncthreads();                      // A pass-tile ready (drains DMA)

    // B fragments in 4-k-step sub-bursts (Bf[4][2]=32 VGPR; unroll 1 keeps
    // the two sub-burst lifetimes disjoint -> no spill)
    #pragma unroll 1
    for (int sb = 0; sb < 2; ++sb){
      short8 Bf[4][2];
      #pragma unroll
      for (int kt2 = 0; kt2 < 4; ++kt2){
        #pragma unroll
        for (int ct = 0; ct < 2; ++ct){
          Bf[kt2][ct] = *(const short8*)(Bt + (size_t)(c0 + ct*16 + l15) * K
                                            + (p*8 + sb*4 + kt2)*32 + quad*8);
        }
      }
      __builtin_amdgcn_sched_barrier(0);
      #pragma unroll
      for (int s = 0; s < 4; ++s){
        int row = s * 16 + l15;
        int swzus = (row & 7) << 3;       // ushort-index XOR = byte XOR >> 1
        const unsigned short* base = Abuf + row * 256;
        #pragma unroll
        for (int kt2 = 0; kt2 < 4; ++kt2){
          short8 af = *(const short8*)(base + (((sb*4 + kt2)*32 + quad*8) ^ swzus));
          acc[s][0] = __builtin_amdgcn_mfma_f32_16x16x32_bf16(af, Bf[kt2][0], acc[s][0], 0, 0, 0);
          acc[s][1] = __builtin_amdgcn_mfma_f32_16x16x32_bf16(af, Bf[kt2][1], acc[s][1], 0, 0, 0);
        }
      }
    }
    // esd columns whose k-range lives in this pass
    #pragma unroll
    for (int i = 0; i < KE; ++i){
      int kt = w * KE + i;
      if (kt >= p*8 && kt < p*8 + 8){
        int kt2 = kt - p*8;
        #pragma unroll
        for (int s = 0; s < 4; ++s){
          int row = s * 16 + l15;
          int swzus = (row & 7) << 3;
          const unsigned short* base = Abuf + row * 256;
          short8 af = *(const short8*)(base + ((kt2*32 + quad*8) ^ swzus));
          eacc[s] = __builtin_amdgcn_mfma_f32_16x16x32_bf16(af, Bfe[i], eacc[s], 0, 0, 0);
        }
      }
    }
  }

  // ---- epilogue: hstage UNIONS onto Abuf ----
  __syncthreads();                        // all Abuf reads complete
  #pragma unroll
  for (int s = 0; s < 4; ++s){
    #pragma unroll
    for (int r = 0; r < 4; ++r){
      int row = s * 16 + quad * 4 + r;
      int swz = (row & 7) << 4;
      #pragma unroll
      for (int ct = 0; ct < 2; ++ct){
        int colb = (c0 + ct * 16 + l15) * 2;
        *(unsigned short*)((char*)Abuf + ((row * 512 + colb) ^ swz))
            = f2bf(acc[s][ct][r]);
      }
      if (l15 < 8) cmbE[w][row][l15] = eacc[s][r];
    }
  }
  __syncthreads();

  // coalesced h stores: full 512B rows
  #pragma unroll
  for (int c = 0; c < 4; ++c){
    int us = (c * 512 + tid) * 8;         // ushort index in 64x256 tile
    int row = us >> 8, col = us & 255;
    int grow = r0 + row;
    if (grow < M){
      uint4 v = *(const uint4*)((const char*)Abuf + ((row * 512 + col * 2) ^ ((row & 7) << 4)));
      *(uint4*)(hb + (size_t)grow * WIDTH + col) = v;
    }
  }
  // es/ed combine + store (separate 16B-row arrays)
  {
    int row = tid >> 3, j = tid & 7;
    int grow = r0 + row;
    if (grow < M){
      float v = 0.f;
      #pragma unroll
      for (int ww = 0; ww < 8; ++ww) v += cmbE[ww][row][j];
      if (j < 4) es[(size_t)grow * 4 + j] = v;
      else       ed[(size_t)grow * 4 + (j - 4)] = v;
    }
  }
}

// ---------------- aggregation: one node per HALF-wave ----------------
__global__ __launch_bounds__(256) void agg_kernel(const int* __restrict__ offsets,
                                                  const int* __restrict__ srcs,
                                                  const float* __restrict__ es,
                                                  const float* __restrict__ ed,
                                                  const unsigned short* __restrict__ hb,
                                                  const float* __restrict__ bias,
                                                  unsigned short* __restrict__ hout){
  __shared__ float eLds[8][64][4];
  __shared__ int   sLds[8][64];
  int wid = threadIdx.x >> 6;
  int lane = threadIdx.x & 63;
  int half = lane >> 5, l32 = lane & 31;
  int slot = wid * 2 + half;
  int n = blockIdx.x * 8 + slot;
  int base = offsets[n];
  int deg = offsets[n + 1] - base;
  float4 edv = *(const float4*)(ed + (size_t)n * 4);

  // pass 1: strided over 32 lanes; cache first 64 edges in LDS; per-head max
  float m0 = -1e30f, m1 = -1e30f, m2 = -1e30f, m3 = -1e30f;
  for (int i = l32; i < deg; i += 32){
    int s = srcs[base + i];
    float4 ev = *(const float4*)(es + (size_t)s * 4);
    float e0 = ev.x + edv.x, e1 = ev.y + edv.y, e2 = ev.z + edv.z, e3 = ev.w + edv.w;
    e0 = e0 > 0.f ? e0 : 0.2f * e0;
    e1 = e1 > 0.f ? e1 : 0.2f * e1;
    e2 = e2 > 0.f ? e2 : 0.2f * e2;
    e3 = e3 > 0.f ? e3 : 0.2f * e3;
    if (i < 64){
      sLds[slot][i] = s;
      *(float4*)(&eLds[slot][i][0]) = (float4){e0, e1, e2, e3};
    }
    m0 = fmaxf(m0, e0); m1 = fmaxf(m1, e1); m2 = fmaxf(m2, e2); m3 = fmaxf(m3, e3);
  }
  #pragma unroll
  for (int off = 1; off < 32; off <<= 1){
    m0 = fmaxf(m0, __shfl_xor(m0, off, 64));
    m1 = fmaxf(m1, __shfl_xor(m1, off, 64));
    m2 = fmaxf(m2, __shfl_xor(m2, off, 64));
    m3 = fmaxf(m3, __shfl_xor(m3, off, 64));
  }
  int head = l32 >> 3;                       // 8 lanes per head, 8 ch/lane
  float mh  = (head == 0) ? m0 : (head == 1) ? m1 : (head == 2) ? m2 : m3;
  float edh = (head == 0) ? edv.x : (head == 1) ? edv.y : (head == 2) ? edv.z : edv.w;

  // pass 2: 8 edges per iteration, 8 gathers in flight
  float2 a0 = {0.f,0.f}, a1 = {0.f,0.f}, a2 = {0.f,0.f}, a3 = {0.f,0.f};
  float den = 0.f;
  const unsigned short* hcol = hb + 8 * l32;
  for (int i = 0; i < deg; i += 8){
    int sidx[8]; float wgt[8];
    #pragma unroll
    for (int u = 0; u < 8; ++u){
      int idx = i + u;
      bool v = idx < deg;
      float le; int s;
      if (idx < 64 || !v){
        int ic = v ? idx : 0;
        if (ic >= 64) ic = 0;
        s  = sLds[slot][ic];
        le = eLds[slot][ic][head];
      } else {
        s = srcs[base + idx];
        float e = es[(size_t)s * 4 + head] + edh;
        le = e > 0.f ? e : 0.2f * e;
      }
      sidx[u] = s;
      wgt[u] = v ? __expf(le - mh) : 0.f;
    }
    uint4 hv[8];
    #pragma unroll
    for (int u = 0; u < 8; ++u)
      hv[u] = *(const uint4*)(hcol + (size_t)sidx[u] * WIDTH);
    #pragma unroll
    for (int u = 0; u < 8; ++u){
      float wu = wgt[u];
      den += wu;
      a0.x += wu * __uint_as_float(hv[u].x << 16);
      a0.y += wu * __uint_as_float(hv[u].x & 0xffff0000u);
      a1.x += wu * __uint_as_float(hv[u].y << 16);
      a1.y += wu * __uint_as_float(hv[u].y & 0xffff0000u);
      a2.x += wu * __uint_as_float(hv[u].z << 16);
      a2.y += wu * __uint_as_float(hv[u].z & 0xffff0000u);
      a3.x += wu * __uint_as_float(hv[u].w << 16);
      a3.y += wu * __uint_as_float(hv[u].w & 0xffff0000u);
    }
  }
  float inv = 1.0f / den;
  const float* bp = bias + 8 * l32;
  float4 bv0 = *(const float4*)(bp);
  float4 bv1 = *(const float4*)(bp + 4);
  float o0 = fmaxf(a0.x * inv + bv0.x, 0.f);
  float o1 = fmaxf(a0.y * inv + bv0.y, 0.f);
  float o2 = fmaxf(a1.x * inv + bv0.z, 0.f);
  float o3 = fmaxf(a1.y * inv + bv0.w, 0.f);
  float o4 = fmaxf(a2.x * inv + bv1.x, 0.f);
  float o5 = fmaxf(a2.y * inv + bv1.y, 0.f);
  float o6 = fmaxf(a3.x * inv + bv1.z, 0.f);
  float o7 = fmaxf(a3.y * inv + bv1.w, 0.f);
  uint4 o;
  o.x = (unsigned)f2bf(o0) | ((unsigned)f2bf(o1) << 16);
  o.y = (unsigned)f2bf(o2) | ((unsigned)f2bf(o3) << 16);
  o.z = (unsigned)f2bf(o4) | ((unsigned)f2bf(o5) << 16);
  o.w = (unsigned)f2bf(o6) | ((unsigned)f2bf(o7) << 16);
  *(uint4*)(hout + (size_t)n * WIDTH + 8 * l32) = o;
}

// ---------------- output head as MFMA GEMM ----------------
__global__ __launch_bounds__(256) void out_gemm_kernel(const unsigned short* __restrict__ h1,
                                                       const unsigned short* __restrict__ h2,
                                                       const unsigned short* __restrict__ h3,
                                                       const unsigned short* __restrict__ WoT,
                                                       const float* __restrict__ bo,
                                                       float* __restrict__ out){
  int tid = threadIdx.x, lane = tid & 63, wid = tid >> 6;
  int l15 = lane & 15, quad = lane >> 4;
  int m0 = blockIdx.x * 64 + 16 * wid;

  f32x4 acc[3];
  #pragma unroll
  for (int t = 0; t < 3; ++t) acc[t] = (f32x4){0.f, 0.f, 0.f, 0.f};

  int arow = m0 + l15; if (arow >= N_NODES) arow = N_NODES - 1;

  #pragma unroll
  for (int part = 0; part < 3; ++part){
    const unsigned short* hp = (part == 0) ? h1 : (part == 1) ? h2 : h3;
    const unsigned short* ap = hp + (size_t)arow * WIDTH;
    #pragma unroll
    for (int k0 = 0; k0 < WIDTH; k0 += 32){
      short8 af = *(const short8*)(ap + k0 + quad * 8);
      int kk = part * WIDTH + k0;
      #pragma unroll
      for (int t = 0; t < 3; ++t){
        short8 bf = *(const short8*)(WoT + (size_t)(16 * t + l15) * KCAT + kk + quad * 8);
        acc[t] = __builtin_amdgcn_mfma_f32_16x16x32_bf16(af, bf, acc[t], 0, 0, 0);
      }
    }
  }

  int r0 = m0 + quad * 4;
  #pragma unroll
  for (int t = 0; t < 3; ++t){
    int col = 16 * t + l15;
    if (col < NCLS){
      float bc = bo[col];
      #pragma unroll
      for (int r = 0; r < 4; ++r){
        int grow = r0 + r;
        if (grow < N_NODES) out[(size_t)grow * NCLS + col] = acc[t][r] + bc;
      }
    }
  }
}

// ---------------- host launch ----------------
static inline size_t align256(size_t x){ return (x + 255) & ~(size_t)255; }

extern "C" void kernel_launch(void* const* d_in, const int* in_sizes, int n_in,
                              void* d_out, int out_size, void* d_ws, size_t ws_size,
                              hipStream_t stream) {
  const float* x   = (const float*)d_in[0];
  const int*   ei  = (const int*)  d_in[1];
  const float* W1  = (const float*)d_in[2];
  const float* as1 = (const float*)d_in[3];
  const float* ad1 = (const float*)d_in[4];
  const float* b1  = (const float*)d_in[5];
  const float* W2  = (const float*)d_in[6];
  const float* as2 = (const float*)d_in[7];
  const float* ad2 = (const float*)d_in[8];
  const float* b2  = (const float*)d_in[9];
  const float* W3  = (const float*)d_in[10];
  const float* as3 = (const float*)d_in[11];
  const float* ad3 = (const float*)d_in[12];
  const float* b3  = (const float*)d_in[13];
  const float* Wo  = (const float*)d_in[14];
  const float* bo  = (const float*)d_in[15];
  float* out = (float*)d_out;

  char* p = (char*)d_ws;
  auto take = [&](size_t bytes) -> char* { char* cur = p; p += align256(bytes); return cur; };

  unsigned short* Wt1   = (unsigned short*)take((size_t)BROWS * F_IN * 2);
  unsigned short* Wt2   = (unsigned short*)take((size_t)BROWS * WIDTH * 2);
  unsigned short* Wt3   = (unsigned short*)take((size_t)BROWS * WIDTH * 2);
  unsigned short* WoT   = (unsigned short*)take((size_t)NPAD * KCAT * 2);
  unsigned short* hs    = (unsigned short*)take((size_t)N_NODES * WIDTH * 2);
  float*          es    = (float*)take((size_t)N_NODES * 4 * 4);
  float*          ed    = (float*)take((size_t)N_NODES * 4 * 4);
  unsigned short* h1b   = (unsigned short*)take((size_t)N_NODES * WIDTH * 2);
  unsigned short* h2b   = (unsigned short*)take((size_t)N_NODES * WIDTH * 2);
  unsigned short* h3b   = (unsigned short*)take((size_t)N_NODES * WIDTH * 2);
  int*            counts  = (int*)take((size_t)N_NODES * 4);
  int*            offsets = (int*)take((size_t)(N_NODES + 1) * 4);
  int*            cursor  = (int*)take((size_t)N_NODES * 4);
  int*            srcs    = (int*)take((size_t)ETOT * 4);
  int*            bsum    = (int*)take((size_t)64 * 4);

  // fused prep: zero + transposes + av folds (1 dispatch)
  prep_kernel<<<PREP_GRID, 256, 0, stream>>>(W1, as1, ad1, W2, as2, ad2,
                                             W3, as3, ad3, Wo,
                                             Wt1, Wt2, Wt3, WoT, counts);

  // CSR build: hist + 3-dispatch parallel scan (scatter fused into gemm1)
  const int nb = (N_NODES + 1023) / 1024;          // 30
  hist_kernel<<<(ETOT + 255) / 256, 256, 0, stream>>>(ei, counts);
  scan_part_kernel<<<nb, 1024, 0, stream>>>(counts, offsets, bsum, N_NODES);
  scan_bsum_kernel<<<1, 64, 0, stream>>>(bsum, offsets, nb, N_NODES);
  scan_add_kernel<<<nb, 1024, 0, stream>>>(offsets, cursor, bsum, N_NODES);

  const int ntiles = (N_NODES + TM - 1) / TM;      // 469
  const int nscat  = (ETOT + 511) / 512;           // 997
  const int agg_grid = N_NODES / 8;                // 3750
  const int out_grid = (N_NODES + 63) / 64;        // 469

  // layer 1 (A = x, f32) + fused scatter blocks
  gemm_bres_kernel<F_IN, true><<<ntiles + nscat, 512, 0, stream>>>(
      x, Wt1, es, ed, hs, N_NODES, ntiles, ei, cursor, srcs);
  agg_kernel<<<agg_grid, 256, 0, stream>>>(offsets, srcs, es, ed, hs, b1, h1b);
  // layer 2
  gemm_bres_kernel<WIDTH, false><<<ntiles, 512, 0, stream>>>(
      h1b, Wt2, es, ed, hs, N_NODES, ntiles, ei, cursor, srcs);
  agg_kernel<<<agg_grid, 256, 0, stream>>>(offsets, srcs, es, ed, hs, b2, h2b);
  // layer 3
  gemm_bres_kernel<WIDTH, false><<<ntiles, 512, 0, stream>>>(
      h2b, Wt3, es, ed, hs, N_NODES, ntiles, ei, cursor, srcs);
  agg_kernel<<<agg_grid, 256, 0, stream>>>(offsets, srcs, es, ed, hs, b3, h3b);

  // output head (MFMA GEMM)
  out_gemm_kernel<<<out_grid, 256, 0, stream>>>(h1b, h2b, h3b, WoT, bo, out);
}

// Round 12
// 360.172 us; speedup vs baseline: 1.0753x; 1.0206x over previous
//
#include <hip/hip_runtime.h>

#define N_NODES 30000
#define N_EDGES 480000
#define ETOT    510000   // edges + self loops
#define F_IN    512
#define WIDTH   256
#define NCLS    40
#define KCAT    768      // WIDTH*3
#define NPAD    48       // NCLS padded to 3 MFMA col-tiles
#define TM      64       // A-tile rows per block (halves B L2 traffic)
#define BROWS   272      // Bt rows: 256 h-cols + 16 esd-cols (8 used)

typedef __attribute__((ext_vector_type(8))) short short8;
typedef __attribute__((ext_vector_type(4))) float f32x4;

__device__ __forceinline__ unsigned short f2bf(float f){
  unsigned u = __float_as_uint(f);
  u += 0x7fffu + ((u >> 16) & 1u);   // RTNE
  return (unsigned short)(u >> 16);
}
__device__ __forceinline__ float b2f(unsigned short s){
  return __uint_as_float(((unsigned)s) << 16);
}

// async global->LDS, 16B per lane. LDS dest must be linear (base + lane*16).
__device__ __forceinline__ void gload_lds16(const void* g, void* l){
  __builtin_amdgcn_global_load_lds(
      (const __attribute__((address_space(1))) unsigned int*)g,
      (__attribute__((address_space(3))) unsigned int*)l, 16, 0, 0);
}

// ---------------- fused prep: zero + all weight transposes + av folds ----------------
__device__ __forceinline__ void av_body(const float* __restrict__ W,
                                        const float* __restrict__ a_s,
                                        const float* __restrict__ a_d,
                                        unsigned short* __restrict__ Bt, int K, int k){
  int tid = threadIdx.x;           // 256 = 4 heads x 64 ch
  int h = tid >> 6, lane = tid & 63;
  float wv = W[(size_t)k * WIDTH + tid];
  float ps = wv * a_s[tid];
  float pd = wv * a_d[tid];
  #pragma unroll
  for (int off = 32; off; off >>= 1){
    ps += __shfl_down(ps, off, 64);
    pd += __shfl_down(pd, off, 64);
  }
  if (lane == 0){
    Bt[(size_t)(256 + h) * K + k] = f2bf(ps);
    Bt[(size_t)(260 + h) * K + k] = f2bf(pd);
  }
  if (tid < 8) Bt[(size_t)(264 + tid) * K + k] = 0;
}

#define PREP_GRID (118 + 512 + 256 + 256 + 144 + 512 + 256 + 256)   // 2310

__global__ __launch_bounds__(256) void prep_kernel(
    const float* __restrict__ W1, const float* __restrict__ as1, const float* __restrict__ ad1,
    const float* __restrict__ W2, const float* __restrict__ as2, const float* __restrict__ ad2,
    const float* __restrict__ W3, const float* __restrict__ as3, const float* __restrict__ ad3,
    const float* __restrict__ Wo,
    unsigned short* __restrict__ Wt1, unsigned short* __restrict__ Wt2,
    unsigned short* __restrict__ Wt3, unsigned short* __restrict__ WoT,
    int* __restrict__ counts){
  int b = blockIdx.x, tid = threadIdx.x;
  if (b < 118){                          // zero counts
    int i = b * 256 + tid;
    if (i < N_NODES) counts[i] = 0;
    return;
  }
  b -= 118;
  if (b < 512){                          // Wt1: W1[512][256] -> [256][512] bf16
    int n = b >> 1, k = (b & 1) * 256 + tid;
    Wt1[(size_t)n * F_IN + k] = f2bf(W1[(size_t)k * WIDTH + n]);
    return;
  }
  b -= 512;
  if (b < 256){ Wt2[(size_t)b * WIDTH + tid] = f2bf(W2[(size_t)tid * WIDTH + b]); return; }
  b -= 256;
  if (b < 256){ Wt3[(size_t)b * WIDTH + tid] = f2bf(W3[(size_t)tid * WIDTH + b]); return; }
  b -= 256;
  if (b < 144){                          // WoT pad+transpose: 48*768
    int i = b * 256 + tid;
    int c = i / KCAT, k = i - c * KCAT;
    WoT[i] = (c < NCLS) ? f2bf(Wo[(size_t)k * NCLS + c]) : (unsigned short)0;
    return;
  }
  b -= 144;
  if (b < 512){ av_body(W1, as1, ad1, Wt1, F_IN, b); return; }
  b -= 512;
  if (b < 256){ av_body(W2, as2, ad2, Wt2, WIDTH, b); return; }
  b -= 256;
  av_body(W3, as3, ad3, Wt3, WIDTH, b);
}

// ---------------- CSR build ----------------
__global__ void hist_kernel(const int* __restrict__ ei, int* __restrict__ counts){
  int e = blockIdx.x * blockDim.x + threadIdx.x;
  if (e < ETOT){
    int d = (e < N_EDGES) ? ei[N_EDGES + e] : (e - N_EDGES);
    atomicAdd(&counts[d], 1);
  }
}

__global__ __launch_bounds__(1024) void scan_part_kernel(const int* __restrict__ counts,
                                                         int* __restrict__ offsets,
                                                         int* __restrict__ bsum, int n){
  __shared__ int wsum[16];
  int tid = threadIdx.x, lane = tid & 63, wid = tid >> 6;
  int i = blockIdx.x * 1024 + tid;
  int v = (i < n) ? counts[i] : 0;
  int x = v;
  #pragma unroll
  for (int off = 1; off < 64; off <<= 1){
    int t = __shfl_up(x, off, 64);
    if (lane >= off) x += t;
  }
  if (lane == 63) wsum[wid] = x;
  __syncthreads();
  if (wid == 0){
    int s = (lane < 16) ? wsum[lane] : 0;
    #pragma unroll
    for (int off = 1; off < 16; off <<= 1){
      int t = __shfl_up(s, off, 64);
      if (lane >= off) s += t;
    }
    if (lane < 16) wsum[lane] = s;
  }
  __syncthreads();
  int wp = (wid > 0) ? wsum[wid - 1] : 0;
  if (i < n) offsets[i] = x - v + wp;       // exclusive within block
  if (tid == 0) bsum[blockIdx.x] = wsum[15];
}

__global__ __launch_bounds__(64) void scan_bsum_kernel(int* __restrict__ bsum,
                                                       int* __restrict__ offsets,
                                                       int nb, int n){
  int lane = threadIdx.x;
  int v = (lane < nb) ? bsum[lane] : 0;
  int x = v;
  #pragma unroll
  for (int off = 1; off < 64; off <<= 1){
    int t = __shfl_up(x, off, 64);
    if (lane >= off) x += t;
  }
  if (lane < nb) bsum[lane] = x - v;        // exclusive block prefix
  if (lane == nb - 1) offsets[n] = x;       // grand total
}

__global__ __launch_bounds__(1024) void scan_add_kernel(int* __restrict__ offsets,
                                                        int* __restrict__ cursor,
                                                        const int* __restrict__ bsum, int n){
  int i = blockIdx.x * 1024 + threadIdx.x;
  if (i < n){
    int o = offsets[i] + bsum[blockIdx.x];
    offsets[i] = o;
    cursor[i] = o;
  }
}

// ---------------- B-reuse fused GEMM, one 64-row tile per block ----------------
// Round-10 structure (PASSED, 367us) with ONE register-pressure fix: the
// esd-MFMA section (es/ed as 8 extra B cols of Bt = W@a precomputed) is now
// PER-PASS. Each wave's esd k-range (kt = w*KE..w*KE+KE-1) lies entirely in
// one K-pass, so Bfe+eacc (24-32 VGPRs) are loaded/accumulated/flushed-to-cmbE
// inside that pass instead of living across the whole kernel. Persistent
// demand drops from ~108 (round-10: VGPR=64 + ~38MB/dispatch spill, WRITE_SIZE
// 54MB vs 16 legit) to acc(32)+Bf-burst(32)+addr ~= 80. Math is IDENTICAL to
// round 10 (same MFMAs, same cmbE[8][TM][9] combine). B in 4-k-step sub-bursts;
// A staged per 256-wide K-pass into 32KB buffer; hstage UNIONS onto it after
// the k-loop. Layer-1 dispatch carries the edge SCATTER as extra blocks.
template<int K, bool AF32>
__global__ __launch_bounds__(512, 4)
void gemm_bres_kernel(const void* __restrict__ Araw,
                      const unsigned short* __restrict__ Bt,
                      float* __restrict__ es,
                      float* __restrict__ ed,
                      unsigned short* __restrict__ hb,
                      int M, int ngb,
                      const int* __restrict__ ei,
                      int* __restrict__ cursor,
                      int* __restrict__ srcs){
  constexpr int KT = K / 32;       // k-steps total (8 or 16)
  constexpr int NP = K / 256;      // K-passes (1 or 2)
  constexpr int KE = KT / 8;       // esd k-steps per wave (1 or 2)
  __shared__ unsigned short Abuf[TM * 256];   // 32KB: A pass-tile, then hstage
  __shared__ float cmbE[8][TM][9];            // 18KB

  int tid = threadIdx.x;

  // ---- fused scatter section (layer-1 dispatch only) ----
  if ((int)blockIdx.x >= ngb){
    int e = ((int)blockIdx.x - ngb) * 512 + tid;
    if (e < ETOT){
      int s, d;
      if (e < N_EDGES){ s = ei[e]; d = ei[N_EDGES + e]; }
      else { s = e - N_EDGES; d = s; }
      int pos = atomicAdd(&cursor[d], 1);
      srcs[pos] = s;
    }
    return;
  }

  int lane = tid & 63, w = tid >> 6;
  int l15 = lane & 15, quad = lane >> 4;
  int c0 = w * 32;
  int r0 = blockIdx.x * TM;

  f32x4 acc[4][2];
  #pragma unroll
  for (int s = 0; s < 4; ++s){
    acc[s][0] = (f32x4){0.f,0.f,0.f,0.f};
    acc[s][1] = (f32x4){0.f,0.f,0.f,0.f};
  }

  // ---- K-pass loop: stage A pass-tile, then ds_read + MFMA ----
  #pragma unroll 1
  for (int p = 0; p < NP; ++p){
    if (p) __syncthreads();               // all reads of prior pass done
    if constexpr (AF32){
      // f32 source: 64 rows x 256 k x 4B per pass; reg-stage + cvt (va dies
      // before MFMA)
      const char* xb = (const char*)Araw;
      uint4 va[8];
      #pragma unroll
      for (int i = 0; i < 8; ++i){
        int L32 = (i * 512 + tid) * 16;   // 0..65535
        int row = L32 >> 10;              // 1024B per row-pass
        int colb = L32 & 1023;
        int grow = r0 + row; if (grow > M - 1) grow = M - 1;
        va[i] = *(const uint4*)(xb + (size_t)grow * (K*4) + p*1024 + colb);
      }
      #pragma unroll
      for (int i = 0; i < 8; ++i){
        int ob = (i * 512 + tid) * 8;     // 0..32767
        int row = ob >> 9;                // 512B per LDS row
        unsigned u0 = (unsigned)f2bf(__uint_as_float(va[i].x)) |
                      ((unsigned)f2bf(__uint_as_float(va[i].y)) << 16);
        unsigned u1 = (unsigned)f2bf(__uint_as_float(va[i].z)) |
                      ((unsigned)f2bf(__uint_as_float(va[i].w)) << 16);
        uint2 uv; uv.x = u0; uv.y = u1;
        *(uint2*)((char*)Abuf + (ob ^ ((row & 7) << 4))) = uv;
      }
    } else {
      const char* Ab = (const char*)Araw;
      #pragma unroll
      for (int c = 0; c < 4; ++c){
        int L = (c * 512 + tid) * 16;     // 0..32767 linear LDS byte offset
        int row = L >> 9;                 // 512B per LDS row
        int colb = L & 511;
        int grow = r0 + row; if (grow > M - 1) grow = M - 1;
        gload_lds16(Ab + (size_t)grow * (K*2) + p*512 + (colb ^ ((row & 7) << 4)),
                    (char*)Abuf + L);
      }
    }
    __syncthreads();                      // A pass-tile ready (drains DMA)

    // B fragments in 4-k-step sub-bursts (Bf[4][2]=32 VGPR; unroll 1 keeps
    // the two sub-burst lifetimes disjoint)
    #pragma unroll 1
    for (int sb = 0; sb < 2; ++sb){
      short8 Bf[4][2];
      #pragma unroll
      for (int kt2 = 0; kt2 < 4; ++kt2){
        #pragma unroll
        for (int ct = 0; ct < 2; ++ct){
          Bf[kt2][ct] = *(const short8*)(Bt + (size_t)(c0 + ct*16 + l15) * K
                                            + (p*8 + sb*4 + kt2)*32 + quad*8);
        }
      }
      __builtin_amdgcn_sched_barrier(0);
      #pragma unroll
      for (int s = 0; s < 4; ++s){
        int row = s * 16 + l15;
        int swzus = (row & 7) << 3;       // ushort-index XOR = byte XOR >> 1
        const unsigned short* base = Abuf + row * 256;
        #pragma unroll
        for (int kt2 = 0; kt2 < 4; ++kt2){
          short8 af = *(const short8*)(base + (((sb*4 + kt2)*32 + quad*8) ^ swzus));
          acc[s][0] = __builtin_amdgcn_mfma_f32_16x16x32_bf16(af, Bf[kt2][0], acc[s][0], 0, 0, 0);
          acc[s][1] = __builtin_amdgcn_mfma_f32_16x16x32_bf16(af, Bf[kt2][1], acc[s][1], 0, 0, 0);
        }
      }
    }

    // esd columns: this wave's entire k-range lives in exactly one pass
    // (K=512: waves 0-3 -> pass 0, 4-7 -> pass 1; K=256: all in pass 0).
    // Bfe+eacc are pass-local -> not live across the kernel (the round-10
    // spill source). Results flushed straight to cmbE (read only after the
    // epilogue barrier).
    if (w * KE >= p * 8 && w * KE < p * 8 + 8){   // wave-uniform branch
      short8 Bfe[KE];
      #pragma unroll
      for (int i = 0; i < KE; ++i){
        Bfe[i] = *(const short8*)(Bt + (size_t)(256 + l15) * K + (w*KE + i)*32 + quad*8);
      }
      f32x4 eacc[4];
      #pragma unroll
      for (int s = 0; s < 4; ++s) eacc[s] = (f32x4){0.f,0.f,0.f,0.f};
      #pragma unroll
      for (int s = 0; s < 4; ++s){
        int row = s * 16 + l15;
        int swzus = (row & 7) << 3;
        const unsigned short* base = Abuf + row * 256;
        #pragma unroll
        for (int i = 0; i < KE; ++i){
          int kt2 = w*KE + i - p*8;
          short8 af = *(const short8*)(base + ((kt2*32 + quad*8) ^ swzus));
          eacc[s] = __builtin_amdgcn_mfma_f32_16x16x32_bf16(af, Bfe[i], eacc[s], 0, 0, 0);
        }
      }
      #pragma unroll
      for (int s = 0; s < 4; ++s){
        #pragma unroll
        for (int r = 0; r < 4; ++r){
          int row = s * 16 + quad * 4 + r;
          if (l15 < 8) cmbE[w][row][l15] = eacc[s][r];
        }
      }
    }
  }

  // ---- epilogue: hstage UNIONS onto Abuf ----
  __syncthreads();                        // all Abuf reads complete
  #pragma unroll
  for (int s = 0; s < 4; ++s){
    #pragma unroll
    for (int r = 0; r < 4; ++r){
      int row = s * 16 + quad * 4 + r;
      int swz = (row & 7) << 4;
      #pragma unroll
      for (int ct = 0; ct < 2; ++ct){
        int colb = (c0 + ct * 16 + l15) * 2;
        *(unsigned short*)((char*)Abuf + ((row * 512 + colb) ^ swz))
            = f2bf(acc[s][ct][r]);
      }
    }
  }
  __syncthreads();

  // coalesced h stores: full 512B rows
  #pragma unroll
  for (int c = 0; c < 4; ++c){
    int us = (c * 512 + tid) * 8;         // ushort index in 64x256 tile
    int row = us >> 8, col = us & 255;
    int grow = r0 + row;
    if (grow < M){
      uint4 v = *(const uint4*)((const char*)Abuf + ((row * 512 + col * 2) ^ ((row & 7) << 4)));
      *(uint4*)(hb + (size_t)grow * WIDTH + col) = v;
    }
  }
  // es/ed combine + store (separate 16B-row arrays)
  {
    int row = tid >> 3, j = tid & 7;
    int grow = r0 + row;
    if (grow < M){
      float v = 0.f;
      #pragma unroll
      for (int ww = 0; ww < 8; ++ww) v += cmbE[ww][row][j];
      if (j < 4) es[(size_t)grow * 4 + j] = v;
      else       ed[(size_t)grow * 4 + (j - 4)] = v;
    }
  }
}

// ---------------- aggregation: one node per HALF-wave ----------------
__global__ __launch_bounds__(256) void agg_kernel(const int* __restrict__ offsets,
                                                  const int* __restrict__ srcs,
                                                  const float* __restrict__ es,
                                                  const float* __restrict__ ed,
                                                  const unsigned short* __restrict__ hb,
                                                  const float* __restrict__ bias,
                                                  unsigned short* __restrict__ hout){
  __shared__ float eLds[8][64][4];
  __shared__ int   sLds[8][64];
  int wid = threadIdx.x >> 6;
  int lane = threadIdx.x & 63;
  int half = lane >> 5, l32 = lane & 31;
  int slot = wid * 2 + half;
  int n = blockIdx.x * 8 + slot;
  int base = offsets[n];
  int deg = offsets[n + 1] - base;
  float4 edv = *(const float4*)(ed + (size_t)n * 4);

  // pass 1: strided over 32 lanes; cache first 64 edges in LDS; per-head max
  float m0 = -1e30f, m1 = -1e30f, m2 = -1e30f, m3 = -1e30f;
  for (int i = l32; i < deg; i += 32){
    int s = srcs[base + i];
    float4 ev = *(const float4*)(es + (size_t)s * 4);
    float e0 = ev.x + edv.x, e1 = ev.y + edv.y, e2 = ev.z + edv.z, e3 = ev.w + edv.w;
    e0 = e0 > 0.f ? e0 : 0.2f * e0;
    e1 = e1 > 0.f ? e1 : 0.2f * e1;
    e2 = e2 > 0.f ? e2 : 0.2f * e2;
    e3 = e3 > 0.f ? e3 : 0.2f * e3;
    if (i < 64){
      sLds[slot][i] = s;
      *(float4*)(&eLds[slot][i][0]) = (float4){e0, e1, e2, e3};
    }
    m0 = fmaxf(m0, e0); m1 = fmaxf(m1, e1); m2 = fmaxf(m2, e2); m3 = fmaxf(m3, e3);
  }
  #pragma unroll
  for (int off = 1; off < 32; off <<= 1){
    m0 = fmaxf(m0, __shfl_xor(m0, off, 64));
    m1 = fmaxf(m1, __shfl_xor(m1, off, 64));
    m2 = fmaxf(m2, __shfl_xor(m2, off, 64));
    m3 = fmaxf(m3, __shfl_xor(m3, off, 64));
  }
  int head = l32 >> 3;                       // 8 lanes per head, 8 ch/lane
  float mh  = (head == 0) ? m0 : (head == 1) ? m1 : (head == 2) ? m2 : m3;
  float edh = (head == 0) ? edv.x : (head == 1) ? edv.y : (head == 2) ? edv.z : edv.w;

  // pass 2: 8 edges per iteration, 8 gathers in flight
  float2 a0 = {0.f,0.f}, a1 = {0.f,0.f}, a2 = {0.f,0.f}, a3 = {0.f,0.f};
  float den = 0.f;
  const unsigned short* hcol = hb + 8 * l32;
  for (int i = 0; i < deg; i += 8){
    int sidx[8]; float wgt[8];
    #pragma unroll
    for (int u = 0; u < 8; ++u){
      int idx = i + u;
      bool v = idx < deg;
      float le; int s;
      if (idx < 64 || !v){
        int ic = v ? idx : 0;
        if (ic >= 64) ic = 0;
        s  = sLds[slot][ic];
        le = eLds[slot][ic][head];
      } else {
        s = srcs[base + idx];
        float e = es[(size_t)s * 4 + head] + edh;
        le = e > 0.f ? e : 0.2f * e;
      }
      sidx[u] = s;
      wgt[u] = v ? __expf(le - mh) : 0.f;
    }
    uint4 hv[8];
    #pragma unroll
    for (int u = 0; u < 8; ++u)
      hv[u] = *(const uint4*)(hcol + (size_t)sidx[u] * WIDTH);
    #pragma unroll
    for (int u = 0; u < 8; ++u){
      float wu = wgt[u];
      den += wu;
      a0.x += wu * __uint_as_float(hv[u].x << 16);
      a0.y += wu * __uint_as_float(hv[u].x & 0xffff0000u);
      a1.x += wu * __uint_as_float(hv[u].y << 16);
      a1.y += wu * __uint_as_float(hv[u].y & 0xffff0000u);
      a2.x += wu * __uint_as_float(hv[u].z << 16);
      a2.y += wu * __uint_as_float(hv[u].z & 0xffff0000u);
      a3.x += wu * __uint_as_float(hv[u].w << 16);
      a3.y += wu * __uint_as_float(hv[u].w & 0xffff0000u);
    }
  }
  float inv = 1.0f / den;
  const float* bp = bias + 8 * l32;
  float4 bv0 = *(const float4*)(bp);
  float4 bv1 = *(const float4*)(bp + 4);
  float o0 = fmaxf(a0.x * inv + bv0.x, 0.f);
  float o1 = fmaxf(a0.y * inv + bv0.y, 0.f);
  float o2 = fmaxf(a1.x * inv + bv0.z, 0.f);
  float o3 = fmaxf(a1.y * inv + bv0.w, 0.f);
  float o4 = fmaxf(a2.x * inv + bv1.x, 0.f);
  float o5 = fmaxf(a2.y * inv + bv1.y, 0.f);
  float o6 = fmaxf(a3.x * inv + bv1.z, 0.f);
  float o7 = fmaxf(a3.y * inv + bv1.w, 0.f);
  uint4 o;
  o.x = (unsigned)f2bf(o0) | ((unsigned)f2bf(o1) << 16);
  o.y = (unsigned)f2bf(o2) | ((unsigned)f2bf(o3) << 16);
  o.z = (unsigned)f2bf(o4) | ((unsigned)f2bf(o5) << 16);
  o.w = (unsigned)f2bf(o6) | ((unsigned)f2bf(o7) << 16);
  *(uint4*)(hout + (size_t)n * WIDTH + 8 * l32) = o;
}

// ---------------- output head as MFMA GEMM ----------------
__global__ __launch_bounds__(256) void out_gemm_kernel(const unsigned short* __restrict__ h1,
                                                       const unsigned short* __restrict__ h2,
                                                       const unsigned short* __restrict__ h3,
                                                       const unsigned short* __restrict__ WoT,
                                                       const float* __restrict__ bo,
                                                       float* __restrict__ out){
  int tid = threadIdx.x, lane = tid & 63, wid = tid >> 6;
  int l15 = lane & 15, quad = lane >> 4;
  int m0 = blockIdx.x * 64 + 16 * wid;

  f32x4 acc[3];
  #pragma unroll
  for (int t = 0; t < 3; ++t) acc[t] = (f32x4){0.f, 0.f, 0.f, 0.f};

  int arow = m0 + l15; if (arow >= N_NODES) arow = N_NODES - 1;

  #pragma unroll
  for (int part = 0; part < 3; ++part){
    const unsigned short* hp = (part == 0) ? h1 : (part == 1) ? h2 : h3;
    const unsigned short* ap = hp + (size_t)arow * WIDTH;
    #pragma unroll
    for (int k0 = 0; k0 < WIDTH; k0 += 32){
      short8 af = *(const short8*)(ap + k0 + quad * 8);
      int kk = part * WIDTH + k0;
      #pragma unroll
      for (int t = 0; t < 3; ++t){
        short8 bf = *(const short8*)(WoT + (size_t)(16 * t + l15) * KCAT + kk + quad * 8);
        acc[t] = __builtin_amdgcn_mfma_f32_16x16x32_bf16(af, bf, acc[t], 0, 0, 0);
      }
    }
  }

  int r0 = m0 + quad * 4;
  #pragma unroll
  for (int t = 0; t < 3; ++t){
    int col = 16 * t + l15;
    if (col < NCLS){
      float bc = bo[col];
      #pragma unroll
      for (int r = 0; r < 4; ++r){
        int grow = r0 + r;
        if (grow < N_NODES) out[(size_t)grow * NCLS + col] = acc[t][r] + bc;
      }
    }
  }
}

// ---------------- host launch ----------------
static inline size_t align256(size_t x){ return (x + 255) & ~(size_t)255; }

extern "C" void kernel_launch(void* const* d_in, const int* in_sizes, int n_in,
                              void* d_out, int out_size, void* d_ws, size_t ws_size,
                              hipStream_t stream) {
  const float* x   = (const float*)d_in[0];
  const int*   ei  = (const int*)  d_in[1];
  const float* W1  = (const float*)d_in[2];
  const float* as1 = (const float*)d_in[3];
  const float* ad1 = (const float*)d_in[4];
  const float* b1  = (const float*)d_in[5];
  const float* W2  = (const float*)d_in[6];
  const float* as2 = (const float*)d_in[7];
  const float* ad2 = (const float*)d_in[8];
  const float* b2  = (const float*)d_in[9];
  const float* W3  = (const float*)d_in[10];
  const float* as3 = (const float*)d_in[11];
  const float* ad3 = (const float*)d_in[12];
  const float* b3  = (const float*)d_in[13];
  const float* Wo  = (const float*)d_in[14];
  const float* bo  = (const float*)d_in[15];
  float* out = (float*)d_out;

  char* p = (char*)d_ws;
  auto take = [&](size_t bytes) -> char* { char* cur = p; p += align256(bytes); return cur; };

  unsigned short* Wt1   = (unsigned short*)take((size_t)BROWS * F_IN * 2);
  unsigned short* Wt2   = (unsigned short*)take((size_t)BROWS * WIDTH * 2);
  unsigned short* Wt3   = (unsigned short*)take((size_t)BROWS * WIDTH * 2);
  unsigned short* WoT   = (unsigned short*)take((size_t)NPAD * KCAT * 2);
  unsigned short* hs    = (unsigned short*)take((size_t)N_NODES * WIDTH * 2);
  float*          es    = (float*)take((size_t)N_NODES * 4 * 4);
  float*          ed    = (float*)take((size_t)N_NODES * 4 * 4);
  unsigned short* h1b   = (unsigned short*)take((size_t)N_NODES * WIDTH * 2);
  unsigned short* h2b   = (unsigned short*)take((size_t)N_NODES * WIDTH * 2);
  unsigned short* h3b   = (unsigned short*)take((size_t)N_NODES * WIDTH * 2);
  int*            counts  = (int*)take((size_t)N_NODES * 4);
  int*            offsets = (int*)take((size_t)(N_NODES + 1) * 4);
  int*            cursor  = (int*)take((size_t)N_NODES * 4);
  int*            srcs    = (int*)take((size_t)ETOT * 4);
  int*            bsum    = (int*)take((size_t)64 * 4);

  // fused prep: zero + transposes + av folds (1 dispatch)
  prep_kernel<<<PREP_GRID, 256, 0, stream>>>(W1, as1, ad1, W2, as2, ad2,
                                             W3, as3, ad3, Wo,
                                             Wt1, Wt2, Wt3, WoT, counts);

  // CSR build: hist + 3-dispatch parallel scan (scatter fused into gemm1)
  const int nb = (N_NODES + 1023) / 1024;          // 30
  hist_kernel<<<(ETOT + 255) / 256, 256, 0, stream>>>(ei, counts);
  scan_part_kernel<<<nb, 1024, 0, stream>>>(counts, offsets, bsum, N_NODES);
  scan_bsum_kernel<<<1, 64, 0, stream>>>(bsum, offsets, nb, N_NODES);
  scan_add_kernel<<<nb, 1024, 0, stream>>>(offsets, cursor, bsum, N_NODES);

  const int ntiles = (N_NODES + TM - 1) / TM;      // 469
  const int nscat  = (ETOT + 511) / 512;           // 997
  const int agg_grid = N_NODES / 8;                // 3750
  const int out_grid = (N_NODES + 63) / 64;        // 469

  // layer 1 (A = x, f32) + fused scatter blocks
  gemm_bres_kernel<F_IN, true><<<ntiles + nscat, 512, 0, stream>>>(
      x, Wt1, es, ed, hs, N_NODES, ntiles, ei, cursor, srcs);
  agg_kernel<<<agg_grid, 256, 0, stream>>>(offsets, srcs, es, ed, hs, b1, h1b);
  // layer 2
  gemm_bres_kernel<WIDTH, false><<<ntiles, 512, 0, stream>>>(
      h1b, Wt2, es, ed, hs, N_NODES, ntiles, ei, cursor, srcs);
  agg_kernel<<<agg_grid, 256, 0, stream>>>(offsets, srcs, es, ed, hs, b2, h2b);
  // layer 3
  gemm_bres_kernel<WIDTH, false><<<ntiles, 512, 0, stream>>>(
      h2b, Wt3, es, ed, hs, N_NODES, ntiles, ei, cursor, srcs);
  agg_kernel<<<agg_grid, 256, 0, stream>>>(offsets, srcs, es, ed, hs, b3, h3b);

  // output head (MFMA GEMM)
  out_gemm_kernel<<<out_grid, 256, 0, stream>>>(h1b, h2b, h3b, WoT, bo, out);
}